// Round 8
// baseline (113.175 us; speedup 1.0000x reference)
//
#include <hip/hip_runtime.h>
#include <hip/hip_bf16.h>
#include <math.h>

#define N 2048
#define NC 8

// ws layout:
//   [0, 64)              : double acc[8]          (zeroed by k_prep block 0)
//   [64, 64+128K)        : float2 pack[8][2048]   {s/ln2, A/ln2} packed by k_prep
//   [64+128K, 64+192K)   : int    lohi[8][2048]   (lo | hi<<16, per ORIGINAL row)
//   [64+192K, +4)        : unsigned counter       (ticket for fused finalize)

#if __has_builtin(__builtin_amdgcn_exp2f)
__device__ __forceinline__ float fexp2(float x) { return __builtin_amdgcn_exp2f(x); }
#else
__device__ __forceinline__ float fexp2(float x) { return exp2f(x); }
#endif
#if __has_builtin(__builtin_amdgcn_logf)
__device__ __forceinline__ float flog2(float x) { return __builtin_amdgcn_logf(x); }
#else
__device__ __forceinline__ float flog2(float x) { return log2f(x); }
#endif

#define INV_LN2 1.4426950408889634f
#define LN2_D   0.6931471805599453
#define CLAMP2  (-144.26950408889634f)   /* -100/ln2 : clamp in log2 domain */

// ---------------- Kernel 1: fused A-sum + counting-rank GT + packing ----------
// REVERTED to R5's measured-best geometry (98.43us): 1024 blocks, 32 j's/block,
// 8 i-slices of 256, 4 blocks/CU. R6's 2048-block push regressed (+2.3us):
// per-block fixed costs (full-column staging, deeper trees) outgrew the
// occupancy gain. k_prep lever is CLOSED at this geometry.
// blocks [0,512):    A[j] = sum_i |s_j - s_i| ; write pack[col][j] = {s,A}/ln2
// blocks [512,1024): counting-rank windows -> lohi
__global__ __launch_bounds__(256) void k_prep(const float* __restrict__ logits,
                                              const float* __restrict__ dur,
                                              const int* __restrict__ ev,
                                              float2* __restrict__ pack,
                                              int* __restrict__ lohi,
                                              double* __restrict__ acc,
                                              unsigned* __restrict__ counter) {
    __shared__ float s[N];                   // 8 KB   (asum)
    __shared__ double part[256];             // 2 KB   (asum)
    __shared__ unsigned long long keys[N];   // 16 KB  (sortgt)
    __shared__ int pr[256], pv[256];         // 2 KB   (sortgt)

    int b = blockIdx.x;
    int tid = threadIdx.x;

    if (b == 0) {  // zero accumulators + ticket for k_bce (stream-ordered)
        if (tid < 8) acc[tid] = 0.0;
        else if (tid == 8) counter[0] = 0u;
    }

    if (b < 512) {
        // ---- A-sum, 32 j's per block, 8 i-slices of 256 (f64: exactness) ----
        int col = b >> 6, chunk = b & 63;
        for (int k = 0; k < N / 256; ++k) {
            int i = tid + k * 256;
            s[i] = logits[i * NC + col];
        }
        __syncthreads();
        int jl = tid & 31, slice = tid >> 5;   // 32 j-lanes x 8 slices
        int j = chunk * 32 + jl;
        float sj = s[j];
        int base = slice * 256;
        double a0 = 0.0, a1 = 0.0, a2 = 0.0, a3 = 0.0;
        #pragma unroll 2
        for (int i = 0; i < 256; i += 4) {
            a0 += (double)fabsf(sj - s[base + i]);
            a1 += (double)fabsf(sj - s[base + i + 1]);
            a2 += (double)fabsf(sj - s[base + i + 2]);
            a3 += (double)fabsf(sj - s[base + i + 3]);
        }
        part[tid] = (a0 + a1) + (a2 + a3);
        __syncthreads();
        if (tid < 32) {
            double v = ((part[tid]       + part[tid + 32])  + (part[tid + 64]  + part[tid + 96])) +
                       ((part[tid + 128] + part[tid + 160]) + (part[tid + 192] + part[tid + 224]));
            pack[col * N + j] = make_float2(sj * INV_LN2, (float)v * INV_LN2);
        }
    } else {
        // ---- counting-rank GT windows, 32 j's per block, 8 slices of 256 ----
        // key = (dur_bits<<32)|(i<<1)|e : ascending u64 == stable ascending by d
        int b2 = b - 512;
        int col = b2 >> 6, chunk = b2 & 63;
        for (int k = 0; k < N / 256; ++k) {
            int i = tid + k * 256;
            unsigned int db = __float_as_uint(dur[i * NC + col]);  // dur in [0,1)
            int e = ev[i * NC + col];
            keys[i] = ((unsigned long long)db << 32) | (unsigned int)((i << 1) | e);
        }
        __syncthreads();
        int jl = tid & 31, slice = tid >> 5;
        int j = chunk * 32 + jl;
        unsigned long long kj = keys[j];
        int base = slice * 256;
        int rank = 0, evlt = 0;
        #pragma unroll 4
        for (int i = 0; i < 256; ++i) {
            unsigned long long ki = keys[base + i];
            int lt = (ki < kj) ? 1 : 0;
            rank += lt;
            evlt += lt & (int)(ki & 1ull);
        }
        pr[tid] = rank;
        pv[tid] = evlt;
        __syncthreads();
        if (tid < 32) {
            int r = ((pr[tid]       + pr[tid + 32])  + (pr[tid + 64]  + pr[tid + 96])) +
                    ((pr[tid + 128] + pr[tid + 160]) + (pr[tid + 192] + pr[tid + 224]));
            int v = ((pv[tid]       + pv[tid + 32])  + (pv[tid + 64]  + pv[tid + 96])) +
                    ((pv[tid + 128] + pv[tid + 160]) + (pv[tid + 192] + pv[tid + 224]));
            int e = (int)(kj & 1ull);
            int hi = e ? (r + 1) : N;
            lohi[col * N + j] = v | (hi << 16);
        }
    }
}

// ---------------- Kernel 2: softmax+BCE --------------------------------------
// R7 EXPERIMENT (one variable vs R5's 98.43us): k_bce occupancy 2x — the same
// mechanism R5 validated on k_prep. Grid 1024 -> 2048 blocks (8 rows/block,
// 2 rows/wave). Was grid-capped at 4 blocks/CU = 4 waves/SIMD with pass 3's
// serially-dependent flog2 chains latency-exposed; now 8 blocks/CU, and the
// per-c arrays halving (4->2 wide) cuts VGPR toward the <=64 needed for
// 8 waves/SIMD. Pass-3 (dominant, ~70% issue) total work invariant; per-block
// fixed costs (staging, pass1/2) double — smaller fraction than R6's k_prep case.
// m0-frame math is frame-invariant (frame terms cancel in a1+rbase and
// mx1-mx2); row-group 16->8 only perturbs f32 rounding.
__global__ __launch_bounds__(256) void k_bce(const float2* __restrict__ pack,
                                             const int* __restrict__ lohi,
                                             double* __restrict__ acc,
                                             unsigned* __restrict__ counter,
                                             float* __restrict__ out) {
    int col = blockIdx.x >> 8;   // 0..7
    int rg  = blockIdx.x & 255;  // 0..255 (8 rows each)
    __shared__ float4 sa4[N / 2];   // 16 KB, LIVE through all passes
    __shared__ double bsum[4];      // block reduction buffer
    int tid = threadIdx.x;
    int wave = tid >> 6, lane = tid & 63;

    const float4* p4 = (const float4*)(pack + (size_t)col * N);
    #pragma unroll
    for (int k = 0; k < 4; ++k) {
        int i = tid + (k << 8);
        sa4[i] = p4[i];
    }
    __syncthreads();

    int row0 = (rg << 3) + (wave << 1);   // 2 rows per wave
    float sc0 = (float)(N - 1 - 2 * row0);

    int lh[2];
    #pragma unroll
    for (int c = 0; c < 2; ++c) lh[c] = lohi[col * N + row0 + c];

    // pass 1: max of row 0 ONLY (m0 frame)
    float m = -INFINITY;
    #pragma unroll
    for (int k = 0; k < 16; ++k) {
        float4 q = sa4[lane + (k << 6)];
        float t0 = fmaf(sc0, q.x, -q.y);
        float t1 = fmaf(sc0, q.z, -q.w);
        m = fmaxf(m, fmaxf(t0, t1));
    }
    #pragma unroll
    for (int off = 32; off > 0; off >>= 1)
        m = fmaxf(m, __shfl_xor(m, off, 64));

    // pass 2: se_c = sum_j 2^(t_c - m0); row 1 by incremental multiply
    float se0 = 0.0f, se1 = 0.0f;
    #pragma unroll
    for (int k = 0; k < 16; ++k) {
        float4 q = sa4[lane + (k << 6)];
        {
            float g = fexp2(-(q.x + q.x));
            float E = fexp2(fmaf(sc0, q.x, -q.y) - m);
            se0 += E; E *= g;
            se1 += E;
        }
        {
            float g = fexp2(-(q.z + q.z));
            float E = fexp2(fmaf(sc0, q.z, -q.w) - m);
            se0 += E; E *= g;
            se1 += E;
        }
    }
    #pragma unroll
    for (int off = 32; off > 0; off >>= 1) {
        se0 += __shfl_xor(se0, off, 64);
        se1 += __shfl_xor(se1, off, 64);
    }
    float se[2] = {se0, se1};

    float C2v[2], yv[2];
    unsigned lo[2], wl[2];
    double rbase = 0.0;
    #pragma unroll
    for (int c = 0; c < 2; ++c) {
        float L2 = flog2(se[c]);
        rbase -= 2048.0 * (double)L2;
        C2v[c] = CLAMP2 + L2;
        lo[c] = (unsigned)(lh[c] & 0xffff);
        wl[c] = (unsigned)((lh[c] >> 16) & 0xffff) - lo[c];
        yv[c] = 1.0f / (float)wl[c];
    }

    // pass 3: a1_c = sum max(log2(se_c - E_c), C2_c); a2_c = windowed (mx1-mx2)
    float a1[2] = {0.0f, 0.0f};
    float a2[2] = {0.0f, 0.0f};
    #pragma unroll
    for (int k = 0; k < 16; ++k) {
        float4 q = sa4[lane + (k << 6)];
        int j0 = (lane + (k << 6)) << 1;
        {
            float tsv = q.x + q.x;
            float g = fexp2(-tsv);
            float x = fmaf(sc0, q.x, -q.y) - m;
            float E = fexp2(x);
            #pragma unroll
            for (int c = 0; c < 2; ++c) {
                float mx2 = fmaxf(flog2(se[c] - E), C2v[c]);
                a1[c] += mx2;
                float mx1 = fmaxf(x, C2v[c]);
                float w = ((unsigned)(j0 - lo[c]) < wl[c]) ? (mx1 - mx2) : 0.0f;
                a2[c] += w;
                E *= g;
                x -= tsv;
            }
        }
        {
            float tsv = q.z + q.z;
            float g = fexp2(-tsv);
            float x = fmaf(sc0, q.z, -q.w) - m;
            float E = fexp2(x);
            #pragma unroll
            for (int c = 0; c < 2; ++c) {
                float mx2 = fmaxf(flog2(se[c] - E), C2v[c]);
                a1[c] += mx2;
                float mx1 = fmaxf(x, C2v[c]);
                float w = ((unsigned)(j0 + 1 - lo[c]) < wl[c]) ? (mx1 - mx2) : 0.0f;
                a2[c] += w;
                E *= g;
                x -= tsv;
            }
        }
    }
    float r = 0.0f;
    #pragma unroll
    for (int c = 0; c < 2; ++c) r += fmaf(yv[c], a2[c], a1[c]);
    #pragma unroll
    for (int off = 32; off > 0; off >>= 1)
        r += __shfl_xor(r, off, 64);

    if (lane == 0) bsum[wave] = rbase + (double)r;
    __syncthreads();
    if (tid == 0) {
        double tot = (bsum[0] + bsum[1]) + (bsum[2] + bsum[3]);
        atomicAdd(&acc[col], LN2_D * tot);
        __threadfence();
        unsigned old = atomicAdd(counter, 1u);
        if (old == (unsigned)(NC * 256 - 1)) {  // last of 2048 blocks
            __threadfence();
            float ssum = 0.0f;
            int cnt = 0;
            for (int c = 0; c < NC; ++c) {
                double av2 = atomicAdd(&acc[c], 0.0);  // device-scope read
                float lc = (float)(-av2 / ((double)N * (double)N));
                if (lc > 0.0f) { ssum += lc; cnt++; }
            }
            out[0] = ssum / (float)(cnt > 0 ? cnt : 1);
        }
    }
}

extern "C" void kernel_launch(void* const* d_in, const int* in_sizes, int n_in,
                              void* d_out, int out_size, void* d_ws, size_t ws_size,
                              hipStream_t stream) {
    const float* logits    = (const float*)d_in[0];
    const int*   events    = (const int*)d_in[1];
    const float* durations = (const float*)d_in[2];
    float* out = (float*)d_out;

    char* ws = (char*)d_ws;
    double*   acc     = (double*)ws;
    float2*   pack    = (float2*)(ws + 64);
    int*      lohi    = (int*)(ws + 64 + (size_t)NC * N * sizeof(float2));
    unsigned* counter = (unsigned*)(ws + 64 + (size_t)NC * N * (sizeof(float2) + sizeof(int)));

    k_prep<<<dim3(1024), 256, 0, stream>>>(logits, durations, events, pack, lohi, acc, counter);
    k_bce<<<dim3(NC * 256), 256, 0, stream>>>(pack, lohi, acc, counter, out);
}

// Round 9
// 97.889 us; speedup vs baseline: 1.1562x; 1.1562x over previous
//
#include <hip/hip_runtime.h>
#include <hip/hip_bf16.h>
#include <math.h>

#define N 2048
#define NC 8

// ws layout:
//   [0, 64)              : double acc[8]          (zeroed by k_prep block 0)
//   [64, 64+128K)        : float2 pack[8][2048]   {s/ln2, A/ln2} packed by k_prep
//   [64+128K, 64+192K)   : int    lohi[8][2048]   (lo | hi<<16, per ORIGINAL row)
//   [64+192K, +4)        : unsigned counter       (ticket for fused finalize)

#if __has_builtin(__builtin_amdgcn_exp2f)
__device__ __forceinline__ float fexp2(float x) { return __builtin_amdgcn_exp2f(x); }
#else
__device__ __forceinline__ float fexp2(float x) { return exp2f(x); }
#endif
#if __has_builtin(__builtin_amdgcn_logf)
__device__ __forceinline__ float flog2(float x) { return __builtin_amdgcn_logf(x); }
#else
__device__ __forceinline__ float flog2(float x) { return log2f(x); }
#endif

#define INV_LN2 1.4426950408889634f
#define LN2_D   0.6931471805599453
#define CLAMP2  (-144.26950408889634f)   /* -100/ln2 : clamp in log2 domain */

// ---------------- Kernel 1: fused A-sum + counting-rank GT + packing ----------
// R5's measured-best geometry (98.43us combo): 1024 blocks, 32 j's/block,
// 8 i-slices of 256, 4 blocks/CU. UNCHANGED.
__global__ __launch_bounds__(256) void k_prep(const float* __restrict__ logits,
                                              const float* __restrict__ dur,
                                              const int* __restrict__ ev,
                                              float2* __restrict__ pack,
                                              int* __restrict__ lohi,
                                              double* __restrict__ acc,
                                              unsigned* __restrict__ counter) {
    __shared__ float s[N];                   // 8 KB   (asum)
    __shared__ double part[256];             // 2 KB   (asum)
    __shared__ unsigned long long keys[N];   // 16 KB  (sortgt)
    __shared__ int pr[256], pv[256];         // 2 KB   (sortgt)

    int b = blockIdx.x;
    int tid = threadIdx.x;

    if (b == 0) {  // zero accumulators + ticket for k_bce (stream-ordered)
        if (tid < 8) acc[tid] = 0.0;
        else if (tid == 8) counter[0] = 0u;
    }

    if (b < 512) {
        // ---- A-sum, 32 j's per block, 8 i-slices of 256 (f64: exactness) ----
        int col = b >> 6, chunk = b & 63;
        for (int k = 0; k < N / 256; ++k) {
            int i = tid + k * 256;
            s[i] = logits[i * NC + col];
        }
        __syncthreads();
        int jl = tid & 31, slice = tid >> 5;   // 32 j-lanes x 8 slices
        int j = chunk * 32 + jl;
        float sj = s[j];
        int base = slice * 256;
        double a0 = 0.0, a1 = 0.0, a2 = 0.0, a3 = 0.0;
        #pragma unroll 2
        for (int i = 0; i < 256; i += 4) {
            a0 += (double)fabsf(sj - s[base + i]);
            a1 += (double)fabsf(sj - s[base + i + 1]);
            a2 += (double)fabsf(sj - s[base + i + 2]);
            a3 += (double)fabsf(sj - s[base + i + 3]);
        }
        part[tid] = (a0 + a1) + (a2 + a3);
        __syncthreads();
        if (tid < 32) {
            double v = ((part[tid]       + part[tid + 32])  + (part[tid + 64]  + part[tid + 96])) +
                       ((part[tid + 128] + part[tid + 160]) + (part[tid + 192] + part[tid + 224]));
            pack[col * N + j] = make_float2(sj * INV_LN2, (float)v * INV_LN2);
        }
    } else {
        // ---- counting-rank GT windows, 32 j's per block, 8 slices of 256 ----
        // key = (dur_bits<<32)|(i<<1)|e : ascending u64 == stable ascending by d
        int b2 = b - 512;
        int col = b2 >> 6, chunk = b2 & 63;
        for (int k = 0; k < N / 256; ++k) {
            int i = tid + k * 256;
            unsigned int db = __float_as_uint(dur[i * NC + col]);  // dur in [0,1)
            int e = ev[i * NC + col];
            keys[i] = ((unsigned long long)db << 32) | (unsigned int)((i << 1) | e);
        }
        __syncthreads();
        int jl = tid & 31, slice = tid >> 5;
        int j = chunk * 32 + jl;
        unsigned long long kj = keys[j];
        int base = slice * 256;
        int rank = 0, evlt = 0;
        #pragma unroll 4
        for (int i = 0; i < 256; ++i) {
            unsigned long long ki = keys[base + i];
            int lt = (ki < kj) ? 1 : 0;
            rank += lt;
            evlt += lt & (int)(ki & 1ull);
        }
        pr[tid] = rank;
        pv[tid] = evlt;
        __syncthreads();
        if (tid < 32) {
            int r = ((pr[tid]       + pr[tid + 32])  + (pr[tid + 64]  + pr[tid + 96])) +
                    ((pr[tid + 128] + pr[tid + 160]) + (pr[tid + 192] + pr[tid + 224]));
            int v = ((pv[tid]       + pv[tid + 32])  + (pv[tid + 64]  + pv[tid + 96])) +
                    ((pv[tid + 128] + pv[tid + 160]) + (pv[tid + 192] + pv[tid + 224]));
            int e = (int)(kj & 1ull);
            int hi = e ? (r + 1) : N;
            lohi[col * N + j] = v | (hi << 16);
        }
    }
}

// ---------------- Kernel 2: softmax+BCE --------------------------------------
// R8 EXPERIMENT vs R5's 98.43 (R7's C=2/2048blk regressed to 58.6us/dispatch
// and is reverted): restore the proven C=4 per-wave structure (4 rows/wave,
// incremental E/g chains, m0 frame) and change ONLY the block grouping:
// 512-thread blocks, 32 rows/block, 512 blocks.
//  - halves per-block fixed cost (one 16KB staging + pass1/2 per 32 rows
//    instead of per 16) — R7 proved fixed costs are a large slice by
//    doubling them; this points the same lever the other way.
//  - doubles waves per resident block (8 vs 4): R7's counters showed
//    effective occupancy (~20%, ~1.6 waves/SIMD) far below resource limits;
//    whatever caps resident blocks, each block now carries 2x the waves.
// Per-wave math byte-equivalent to r12; bsum[8]; ticket = 512 blocks.
__global__ __launch_bounds__(512) void k_bce(const float2* __restrict__ pack,
                                             const int* __restrict__ lohi,
                                             double* __restrict__ acc,
                                             unsigned* __restrict__ counter,
                                             float* __restrict__ out) {
    int col = blockIdx.x >> 6;   // 0..7
    int rg  = blockIdx.x & 63;   // 0..63 (32 rows each)
    __shared__ float4 sa4[N / 2];   // 16 KB, LIVE through all passes
    __shared__ double bsum[8];      // block reduction buffer (8 waves)
    int tid = threadIdx.x;
    int wave = tid >> 6, lane = tid & 63;

    const float4* p4 = (const float4*)(pack + (size_t)col * N);
    #pragma unroll
    for (int k = 0; k < 2; ++k) {
        int i = tid + (k << 9);
        sa4[i] = p4[i];
    }
    __syncthreads();

    int row0 = (rg << 5) + (wave << 2);   // 4 rows per wave, 8 waves
    float sc0 = (float)(N - 1 - 2 * row0);

    int lh[4];
    #pragma unroll
    for (int c = 0; c < 4; ++c) lh[c] = lohi[col * N + row0 + c];

    // pass 1: max of row 0 ONLY (m0 frame)
    float m = -INFINITY;
    #pragma unroll
    for (int k = 0; k < 16; ++k) {
        float4 q = sa4[lane + (k << 6)];
        float t0 = fmaf(sc0, q.x, -q.y);
        float t1 = fmaf(sc0, q.z, -q.w);
        m = fmaxf(m, fmaxf(t0, t1));
    }
    #pragma unroll
    for (int off = 32; off > 0; off >>= 1)
        m = fmaxf(m, __shfl_xor(m, off, 64));

    // pass 2: se_c = sum_j 2^(t_c - m0); rows 1..3 by incremental multiply
    float se0 = 0.0f, se1 = 0.0f, se2 = 0.0f, se3 = 0.0f;
    #pragma unroll
    for (int k = 0; k < 16; ++k) {
        float4 q = sa4[lane + (k << 6)];
        {
            float g = fexp2(-(q.x + q.x));
            float E = fexp2(fmaf(sc0, q.x, -q.y) - m);
            se0 += E; E *= g;
            se1 += E; E *= g;
            se2 += E; E *= g;
            se3 += E;
        }
        {
            float g = fexp2(-(q.z + q.z));
            float E = fexp2(fmaf(sc0, q.z, -q.w) - m);
            se0 += E; E *= g;
            se1 += E; E *= g;
            se2 += E; E *= g;
            se3 += E;
        }
    }
    #pragma unroll
    for (int off = 32; off > 0; off >>= 1) {
        se0 += __shfl_xor(se0, off, 64);
        se1 += __shfl_xor(se1, off, 64);
        se2 += __shfl_xor(se2, off, 64);
        se3 += __shfl_xor(se3, off, 64);
    }
    float se[4] = {se0, se1, se2, se3};

    float C2v[4], yv[4];
    unsigned lo[4], wl[4];
    double rbase = 0.0;
    #pragma unroll
    for (int c = 0; c < 4; ++c) {
        float L2 = flog2(se[c]);
        rbase -= 2048.0 * (double)L2;
        C2v[c] = CLAMP2 + L2;
        lo[c] = (unsigned)(lh[c] & 0xffff);
        wl[c] = (unsigned)((lh[c] >> 16) & 0xffff) - lo[c];
        yv[c] = 1.0f / (float)wl[c];
    }

    // pass 3: a1_c = sum max(log2(se_c - E_c), C2_c); a2_c = windowed (mx1-mx2)
    float a1[4] = {0.0f, 0.0f, 0.0f, 0.0f};
    float a2[4] = {0.0f, 0.0f, 0.0f, 0.0f};
    #pragma unroll
    for (int k = 0; k < 16; ++k) {
        float4 q = sa4[lane + (k << 6)];
        int j0 = (lane + (k << 6)) << 1;
        {
            float tsv = q.x + q.x;
            float g = fexp2(-tsv);
            float x = fmaf(sc0, q.x, -q.y) - m;
            float E = fexp2(x);
            #pragma unroll
            for (int c = 0; c < 4; ++c) {
                float mx2 = fmaxf(flog2(se[c] - E), C2v[c]);
                a1[c] += mx2;
                float mx1 = fmaxf(x, C2v[c]);
                float w = ((unsigned)(j0 - lo[c]) < wl[c]) ? (mx1 - mx2) : 0.0f;
                a2[c] += w;
                E *= g;
                x -= tsv;
            }
        }
        {
            float tsv = q.z + q.z;
            float g = fexp2(-tsv);
            float x = fmaf(sc0, q.z, -q.w) - m;
            float E = fexp2(x);
            #pragma unroll
            for (int c = 0; c < 4; ++c) {
                float mx2 = fmaxf(flog2(se[c] - E), C2v[c]);
                a1[c] += mx2;
                float mx1 = fmaxf(x, C2v[c]);
                float w = ((unsigned)(j0 + 1 - lo[c]) < wl[c]) ? (mx1 - mx2) : 0.0f;
                a2[c] += w;
                E *= g;
                x -= tsv;
            }
        }
    }
    float r = 0.0f;
    #pragma unroll
    for (int c = 0; c < 4; ++c) r += fmaf(yv[c], a2[c], a1[c]);
    #pragma unroll
    for (int off = 32; off > 0; off >>= 1)
        r += __shfl_xor(r, off, 64);

    if (lane == 0) bsum[wave] = rbase + (double)r;
    __syncthreads();
    if (tid == 0) {
        double tot = ((bsum[0] + bsum[1]) + (bsum[2] + bsum[3])) +
                     ((bsum[4] + bsum[5]) + (bsum[6] + bsum[7]));
        atomicAdd(&acc[col], LN2_D * tot);
        __threadfence();
        unsigned old = atomicAdd(counter, 1u);
        if (old == (unsigned)(NC * 64 - 1)) {  // last of 512 blocks
            __threadfence();
            float ssum = 0.0f;
            int cnt = 0;
            for (int c = 0; c < NC; ++c) {
                double av2 = atomicAdd(&acc[c], 0.0);  // device-scope read
                float lc = (float)(-av2 / ((double)N * (double)N));
                if (lc > 0.0f) { ssum += lc; cnt++; }
            }
            out[0] = ssum / (float)(cnt > 0 ? cnt : 1);
        }
    }
}

extern "C" void kernel_launch(void* const* d_in, const int* in_sizes, int n_in,
                              void* d_out, int out_size, void* d_ws, size_t ws_size,
                              hipStream_t stream) {
    const float* logits    = (const float*)d_in[0];
    const int*   events    = (const int*)d_in[1];
    const float* durations = (const float*)d_in[2];
    float* out = (float*)d_out;

    char* ws = (char*)d_ws;
    double*   acc     = (double*)ws;
    float2*   pack    = (float2*)(ws + 64);
    int*      lohi    = (int*)(ws + 64 + (size_t)NC * N * sizeof(float2));
    unsigned* counter = (unsigned*)(ws + 64 + (size_t)NC * N * (sizeof(float2) + sizeof(int)));

    k_prep<<<dim3(1024), 256, 0, stream>>>(logits, durations, events, pack, lohi, acc, counter);
    k_bce<<<dim3(NC * 64), 512, 0, stream>>>(pack, lohi, acc, counter, out);
}

// Round 10
// 96.753 us; speedup vs baseline: 1.1697x; 1.0117x over previous
//
#include <hip/hip_runtime.h>
#include <hip/hip_bf16.h>
#include <math.h>

#define N 2048
#define NC 8

// ws layout:
//   [0, 64)              : double acc[8]          (zeroed by k_prep block 0)
//   [64, 64+128K)        : float2 pack[8][2048]   {s/ln2, A/ln2} packed by k_prep
//   [64+128K, 64+192K)   : int    lohi[8][2048]   (lo | hi<<16, per ORIGINAL row)
//   [64+192K, +4)        : unsigned counter       (ticket for fused finalize)

#if __has_builtin(__builtin_amdgcn_exp2f)
__device__ __forceinline__ float fexp2(float x) { return __builtin_amdgcn_exp2f(x); }
#else
__device__ __forceinline__ float fexp2(float x) { return exp2f(x); }
#endif
#if __has_builtin(__builtin_amdgcn_logf)
__device__ __forceinline__ float flog2(float x) { return __builtin_amdgcn_logf(x); }
#else
__device__ __forceinline__ float flog2(float x) { return log2f(x); }
#endif

#define INV_LN2 1.4426950408889634f
#define LN2_D   0.6931471805599453
#define CLAMP2  (-144.26950408889634f)   /* -100/ln2 : clamp in log2 domain */

// ---------------- Kernel 1: fused A-sum + counting-rank GT + packing ----------
// R9 EXPERIMENT (one variable): LDS access width. Instruction accounting says
// the asum loop's 256x ds_read_b32/thread (and sortgt's 256x ds_read_b64) put
// k_prep on the LDS pipe (~5.8-12 cyc/instr), not the f64 VALU chain. Switch
// to ds_read_b128: float4 (4 scores/read) and ulonglong2 (2 keys/read).
// Accumulator mapping q.x/.y/.z/.w == old i,i+1,i+2,i+3 -> a0..a3: A is
// BITWISE identical (absmax must stay exactly 0.0 — deviation flags a bug).
// Geometry unchanged from R5's best: 1024 blocks, 32 j's/block, 8 slices of 256.
__global__ __launch_bounds__(256) void k_prep(const float* __restrict__ logits,
                                              const float* __restrict__ dur,
                                              const int* __restrict__ ev,
                                              float2* __restrict__ pack,
                                              int* __restrict__ lohi,
                                              double* __restrict__ acc,
                                              unsigned* __restrict__ counter) {
    __shared__ __align__(16) float s[N];                   // 8 KB   (asum)
    __shared__ double part[256];                           // 2 KB   (asum)
    __shared__ __align__(16) unsigned long long keys[N];   // 16 KB  (sortgt)
    __shared__ int pr[256], pv[256];                       // 2 KB   (sortgt)

    int b = blockIdx.x;
    int tid = threadIdx.x;

    if (b == 0) {  // zero accumulators + ticket for k_bce (stream-ordered)
        if (tid < 8) acc[tid] = 0.0;
        else if (tid == 8) counter[0] = 0u;
    }

    if (b < 512) {
        // ---- A-sum, 32 j's per block, 8 i-slices of 256 (f64: exactness) ----
        int col = b >> 6, chunk = b & 63;
        for (int k = 0; k < N / 256; ++k) {
            int i = tid + k * 256;
            s[i] = logits[i * NC + col];
        }
        __syncthreads();
        int jl = tid & 31, slice = tid >> 5;   // 32 j-lanes x 8 slices
        int j = chunk * 32 + jl;
        float sj = s[j];
        const float4* s4 = (const float4*)(s + slice * 256);  // 1KB-aligned base
        double a0 = 0.0, a1 = 0.0, a2 = 0.0, a3 = 0.0;
        #pragma unroll 2
        for (int i = 0; i < 64; ++i) {
            float4 q = s4[i];
            a0 += (double)fabsf(sj - q.x);
            a1 += (double)fabsf(sj - q.y);
            a2 += (double)fabsf(sj - q.z);
            a3 += (double)fabsf(sj - q.w);
        }
        part[tid] = (a0 + a1) + (a2 + a3);
        __syncthreads();
        if (tid < 32) {
            double v = ((part[tid]       + part[tid + 32])  + (part[tid + 64]  + part[tid + 96])) +
                       ((part[tid + 128] + part[tid + 160]) + (part[tid + 192] + part[tid + 224]));
            pack[col * N + j] = make_float2(sj * INV_LN2, (float)v * INV_LN2);
        }
    } else {
        // ---- counting-rank GT windows, 32 j's per block, 8 slices of 256 ----
        // key = (dur_bits<<32)|(i<<1)|e : ascending u64 == stable ascending by d
        int b2 = b - 512;
        int col = b2 >> 6, chunk = b2 & 63;
        for (int k = 0; k < N / 256; ++k) {
            int i = tid + k * 256;
            unsigned int db = __float_as_uint(dur[i * NC + col]);  // dur in [0,1)
            int e = ev[i * NC + col];
            keys[i] = ((unsigned long long)db << 32) | (unsigned int)((i << 1) | e);
        }
        __syncthreads();
        int jl = tid & 31, slice = tid >> 5;
        int j = chunk * 32 + jl;
        unsigned long long kj = keys[j];
        const ulonglong2* k2 = (const ulonglong2*)(keys + slice * 256);  // 2KB-aligned
        int rank = 0, evlt = 0;
        #pragma unroll 2
        for (int i = 0; i < 128; ++i) {
            ulonglong2 kk = k2[i];
            int lt0 = (kk.x < kj) ? 1 : 0;
            rank += lt0;
            evlt += lt0 & (int)(kk.x & 1ull);
            int lt1 = (kk.y < kj) ? 1 : 0;
            rank += lt1;
            evlt += lt1 & (int)(kk.y & 1ull);
        }
        pr[tid] = rank;
        pv[tid] = evlt;
        __syncthreads();
        if (tid < 32) {
            int r = ((pr[tid]       + pr[tid + 32])  + (pr[tid + 64]  + pr[tid + 96])) +
                    ((pr[tid + 128] + pr[tid + 160]) + (pr[tid + 192] + pr[tid + 224]));
            int v = ((pv[tid]       + pv[tid + 32])  + (pv[tid + 64]  + pv[tid + 96])) +
                    ((pv[tid + 128] + pv[tid + 160]) + (pv[tid + 192] + pv[tid + 224]));
            int e = (int)(kj & 1ull);
            int hi = e ? (r + 1) : N;
            lohi[col * N + j] = v | (hi << 16);
        }
    }
}

// ---------------- Kernel 2: softmax+BCE — BYTE-IDENTICAL to R8 (97.89us) ------
// 512-thread blocks, 32 rows/block, 512 blocks; proven C=4 per-wave structure.
__global__ __launch_bounds__(512) void k_bce(const float2* __restrict__ pack,
                                             const int* __restrict__ lohi,
                                             double* __restrict__ acc,
                                             unsigned* __restrict__ counter,
                                             float* __restrict__ out) {
    int col = blockIdx.x >> 6;   // 0..7
    int rg  = blockIdx.x & 63;   // 0..63 (32 rows each)
    __shared__ float4 sa4[N / 2];   // 16 KB, LIVE through all passes
    __shared__ double bsum[8];      // block reduction buffer (8 waves)
    int tid = threadIdx.x;
    int wave = tid >> 6, lane = tid & 63;

    const float4* p4 = (const float4*)(pack + (size_t)col * N);
    #pragma unroll
    for (int k = 0; k < 2; ++k) {
        int i = tid + (k << 9);
        sa4[i] = p4[i];
    }
    __syncthreads();

    int row0 = (rg << 5) + (wave << 2);   // 4 rows per wave, 8 waves
    float sc0 = (float)(N - 1 - 2 * row0);

    int lh[4];
    #pragma unroll
    for (int c = 0; c < 4; ++c) lh[c] = lohi[col * N + row0 + c];

    // pass 1: max of row 0 ONLY (m0 frame)
    float m = -INFINITY;
    #pragma unroll
    for (int k = 0; k < 16; ++k) {
        float4 q = sa4[lane + (k << 6)];
        float t0 = fmaf(sc0, q.x, -q.y);
        float t1 = fmaf(sc0, q.z, -q.w);
        m = fmaxf(m, fmaxf(t0, t1));
    }
    #pragma unroll
    for (int off = 32; off > 0; off >>= 1)
        m = fmaxf(m, __shfl_xor(m, off, 64));

    // pass 2: se_c = sum_j 2^(t_c - m0); rows 1..3 by incremental multiply
    float se0 = 0.0f, se1 = 0.0f, se2 = 0.0f, se3 = 0.0f;
    #pragma unroll
    for (int k = 0; k < 16; ++k) {
        float4 q = sa4[lane + (k << 6)];
        {
            float g = fexp2(-(q.x + q.x));
            float E = fexp2(fmaf(sc0, q.x, -q.y) - m);
            se0 += E; E *= g;
            se1 += E; E *= g;
            se2 += E; E *= g;
            se3 += E;
        }
        {
            float g = fexp2(-(q.z + q.z));
            float E = fexp2(fmaf(sc0, q.z, -q.w) - m);
            se0 += E; E *= g;
            se1 += E; E *= g;
            se2 += E; E *= g;
            se3 += E;
        }
    }
    #pragma unroll
    for (int off = 32; off > 0; off >>= 1) {
        se0 += __shfl_xor(se0, off, 64);
        se1 += __shfl_xor(se1, off, 64);
        se2 += __shfl_xor(se2, off, 64);
        se3 += __shfl_xor(se3, off, 64);
    }
    float se[4] = {se0, se1, se2, se3};

    float C2v[4], yv[4];
    unsigned lo[4], wl[4];
    double rbase = 0.0;
    #pragma unroll
    for (int c = 0; c < 4; ++c) {
        float L2 = flog2(se[c]);
        rbase -= 2048.0 * (double)L2;
        C2v[c] = CLAMP2 + L2;
        lo[c] = (unsigned)(lh[c] & 0xffff);
        wl[c] = (unsigned)((lh[c] >> 16) & 0xffff) - lo[c];
        yv[c] = 1.0f / (float)wl[c];
    }

    // pass 3: a1_c = sum max(log2(se_c - E_c), C2_c); a2_c = windowed (mx1-mx2)
    float a1[4] = {0.0f, 0.0f, 0.0f, 0.0f};
    float a2[4] = {0.0f, 0.0f, 0.0f, 0.0f};
    #pragma unroll
    for (int k = 0; k < 16; ++k) {
        float4 q = sa4[lane + (k << 6)];
        int j0 = (lane + (k << 6)) << 1;
        {
            float tsv = q.x + q.x;
            float g = fexp2(-tsv);
            float x = fmaf(sc0, q.x, -q.y) - m;
            float E = fexp2(x);
            #pragma unroll
            for (int c = 0; c < 4; ++c) {
                float mx2 = fmaxf(flog2(se[c] - E), C2v[c]);
                a1[c] += mx2;
                float mx1 = fmaxf(x, C2v[c]);
                float w = ((unsigned)(j0 - lo[c]) < wl[c]) ? (mx1 - mx2) : 0.0f;
                a2[c] += w;
                E *= g;
                x -= tsv;
            }
        }
        {
            float tsv = q.z + q.z;
            float g = fexp2(-tsv);
            float x = fmaf(sc0, q.z, -q.w) - m;
            float E = fexp2(x);
            #pragma unroll
            for (int c = 0; c < 4; ++c) {
                float mx2 = fmaxf(flog2(se[c] - E), C2v[c]);
                a1[c] += mx2;
                float mx1 = fmaxf(x, C2v[c]);
                float w = ((unsigned)(j0 + 1 - lo[c]) < wl[c]) ? (mx1 - mx2) : 0.0f;
                a2[c] += w;
                E *= g;
                x -= tsv;
            }
        }
    }
    float r = 0.0f;
    #pragma unroll
    for (int c = 0; c < 4; ++c) r += fmaf(yv[c], a2[c], a1[c]);
    #pragma unroll
    for (int off = 32; off > 0; off >>= 1)
        r += __shfl_xor(r, off, 64);

    if (lane == 0) bsum[wave] = rbase + (double)r;
    __syncthreads();
    if (tid == 0) {
        double tot = ((bsum[0] + bsum[1]) + (bsum[2] + bsum[3])) +
                     ((bsum[4] + bsum[5]) + (bsum[6] + bsum[7]));
        atomicAdd(&acc[col], LN2_D * tot);
        __threadfence();
        unsigned old = atomicAdd(counter, 1u);
        if (old == (unsigned)(NC * 64 - 1)) {  // last of 512 blocks
            __threadfence();
            float ssum = 0.0f;
            int cnt = 0;
            for (int c = 0; c < NC; ++c) {
                double av2 = atomicAdd(&acc[c], 0.0);  // device-scope read
                float lc = (float)(-av2 / ((double)N * (double)N));
                if (lc > 0.0f) { ssum += lc; cnt++; }
            }
            out[0] = ssum / (float)(cnt > 0 ? cnt : 1);
        }
    }
}

extern "C" void kernel_launch(void* const* d_in, const int* in_sizes, int n_in,
                              void* d_out, int out_size, void* d_ws, size_t ws_size,
                              hipStream_t stream) {
    const float* logits    = (const float*)d_in[0];
    const int*   events    = (const int*)d_in[1];
    const float* durations = (const float*)d_in[2];
    float* out = (float*)d_out;

    char* ws = (char*)d_ws;
    double*   acc     = (double*)ws;
    float2*   pack    = (float2*)(ws + 64);
    int*      lohi    = (int*)(ws + 64 + (size_t)NC * N * sizeof(float2));
    unsigned* counter = (unsigned*)(ws + 64 + (size_t)NC * N * (sizeof(float2) + sizeof(int)));

    k_prep<<<dim3(1024), 256, 0, stream>>>(logits, durations, events, pack, lohi, acc, counter);
    k_bce<<<dim3(NC * 64), 512, 0, stream>>>(pack, lohi, acc, counter, out);
}

// Round 11
// 91.650 us; speedup vs baseline: 1.2349x; 1.0557x over previous
//
#include <hip/hip_runtime.h>
#include <hip/hip_bf16.h>
#include <math.h>

#define N 2048
#define NC 8

// ws layout:
//   [0, 64)                  : double acc[8]            (zeroed by k_prep block 0)
//   [64, 64+128K)            : float2 psort[8][2048]    {s/ln2, A/ln2} in SCORE-SORTED order
//   [64+128K, 64+192K)       : int    lohi[8][2048]     (lo | hi<<16, per ORIGINAL row)
//   [64+192K, +4)            : unsigned counter         (ticket for fused finalize)
//   [64+192K+64, +32K)       : u16    origj[8][2048]    (sorted pos -> original j)

#if __has_builtin(__builtin_amdgcn_exp2f)
__device__ __forceinline__ float fexp2(float x) { return __builtin_amdgcn_exp2f(x); }
#else
__device__ __forceinline__ float fexp2(float x) { return exp2f(x); }
#endif
#if __has_builtin(__builtin_amdgcn_logf)
__device__ __forceinline__ float flog2(float x) { return __builtin_amdgcn_logf(x); }
#else
__device__ __forceinline__ float flog2(float x) { return log2f(x); }
#endif

#define INV_LN2 1.4426950408889634f
#define LN2_D   0.6931471805599453
#define CLAMP2  (-144.26950408889634f)   /* -100/ln2 : clamp in log2 domain */

// ---------------- Kernel 1: A-sum + score-rank + counting-rank GT -------------
// R11: asum half ALSO computes score-rank (strict lex order, index tie-break =>
// valid permutation) and scatters psort[rank]={s,A}/ln2, origj[rank]=j.
// Rank adds 3 compares/element to the proven R10 b128 loop. sortgt unchanged.
__global__ __launch_bounds__(256) void k_prep(const float* __restrict__ logits,
                                              const float* __restrict__ dur,
                                              const int* __restrict__ ev,
                                              float2* __restrict__ psort,
                                              unsigned short* __restrict__ origj,
                                              int* __restrict__ lohi,
                                              double* __restrict__ acc,
                                              unsigned* __restrict__ counter) {
    __shared__ __align__(16) float s[N];                   // 8 KB   (asum)
    __shared__ double part[256];                           // 2 KB   (asum)
    __shared__ int pri[256];                               // 1 KB   (asum rank)
    __shared__ __align__(16) unsigned long long keys[N];   // 16 KB  (sortgt)
    __shared__ int pr[256], pv[256];                       // 2 KB   (sortgt)

    int b = blockIdx.x;
    int tid = threadIdx.x;

    if (b == 0) {  // zero accumulators + ticket for k_bce (stream-ordered)
        if (tid < 8) acc[tid] = 0.0;
        else if (tid == 8) counter[0] = 0u;
    }

    if (b < 512) {
        // ---- A-sum + rank, 32 j's per block, 8 i-slices of 256 ----
        int col = b >> 6, chunk = b & 63;
        for (int k = 0; k < N / 256; ++k) {
            int i = tid + k * 256;
            s[i] = logits[i * NC + col];
        }
        __syncthreads();
        int jl = tid & 31, slice = tid >> 5;   // 32 j-lanes x 8 slices
        int j = chunk * 32 + jl;
        float sj = s[j];
        const float4* s4 = (const float4*)(s + slice * 256);
        int ib = slice * 256;
        double a0 = 0.0, a1 = 0.0, a2 = 0.0, a3 = 0.0;
        int rk = 0;
        #pragma unroll 2
        for (int i = 0; i < 64; ++i) {
            float4 q = s4[i];
            int i0 = ib + 4 * i;
            a0 += (double)fabsf(sj - q.x);
            a1 += (double)fabsf(sj - q.y);
            a2 += (double)fabsf(sj - q.z);
            a3 += (double)fabsf(sj - q.w);
            rk += ((int)(q.x < sj)) | (((int)(q.x == sj)) & (int)(i0 + 0 < j));
            rk += ((int)(q.y < sj)) | (((int)(q.y == sj)) & (int)(i0 + 1 < j));
            rk += ((int)(q.z < sj)) | (((int)(q.z == sj)) & (int)(i0 + 2 < j));
            rk += ((int)(q.w < sj)) | (((int)(q.w == sj)) & (int)(i0 + 3 < j));
        }
        part[tid] = (a0 + a1) + (a2 + a3);
        pri[tid] = rk;
        __syncthreads();
        if (tid < 32) {
            double v = ((part[tid]       + part[tid + 32])  + (part[tid + 64]  + part[tid + 96])) +
                       ((part[tid + 128] + part[tid + 160]) + (part[tid + 192] + part[tid + 224]));
            int r = ((pri[tid]       + pri[tid + 32])  + (pri[tid + 64]  + pri[tid + 96])) +
                    ((pri[tid + 128] + pri[tid + 160]) + (pri[tid + 192] + pri[tid + 224]));
            psort[col * N + r] = make_float2(sj * INV_LN2, (float)v * INV_LN2);
            origj[col * N + r] = (unsigned short)j;
        }
    } else {
        // ---- counting-rank GT windows (UNCHANGED, R10 b128 form) ----
        int b2 = b - 512;
        int col = b2 >> 6, chunk = b2 & 63;
        for (int k = 0; k < N / 256; ++k) {
            int i = tid + k * 256;
            unsigned int db = __float_as_uint(dur[i * NC + col]);  // dur in [0,1)
            int e = ev[i * NC + col];
            keys[i] = ((unsigned long long)db << 32) | (unsigned int)((i << 1) | e);
        }
        __syncthreads();
        int jl = tid & 31, slice = tid >> 5;
        int j = chunk * 32 + jl;
        unsigned long long kj = keys[j];
        const ulonglong2* k2 = (const ulonglong2*)(keys + slice * 256);
        int rank = 0, evlt = 0;
        #pragma unroll 2
        for (int i = 0; i < 128; ++i) {
            ulonglong2 kk = k2[i];
            int lt0 = (kk.x < kj) ? 1 : 0;
            rank += lt0;
            evlt += lt0 & (int)(kk.x & 1ull);
            int lt1 = (kk.y < kj) ? 1 : 0;
            rank += lt1;
            evlt += lt1 & (int)(kk.y & 1ull);
        }
        pr[tid] = rank;
        pv[tid] = evlt;
        __syncthreads();
        if (tid < 32) {
            int r = ((pr[tid]       + pr[tid + 32])  + (pr[tid + 64]  + pr[tid + 96])) +
                    ((pr[tid + 128] + pr[tid + 160]) + (pr[tid + 192] + pr[tid + 224]));
            int v = ((pv[tid]       + pv[tid + 32])  + (pv[tid + 64]  + pv[tid + 96])) +
                    ((pv[tid + 128] + pv[tid + 160]) + (pv[tid + 192] + pv[tid + 224]));
            int e = (int)(kj & 1ull);
            int hi = e ? (r + 1) : N;
            lohi[col * N + j] = v | (hi << 16);
        }
    }
}

// ---------------- Kernel 2: softmax+BCE with sorted-order underflow skip ------
// R11: elements iterated in SCORE-SORTED order. Hot (non-underflowed) set is a
// contiguous interval (t(s) concave) => wave-uniform __all(E0==0) skip on ~2/3
// of k-iterations. Skip branch is BITWISE-faithful: E==+0 propagates through
// the E*=g chain exactly as the full kernel computes; mx2=fmax(flog2(se-0),C2)
// == L2[c] (same instr, same input). Only delta vs R10: j-summation ORDER.
__global__ __launch_bounds__(512) void k_bce(const float2* __restrict__ psort,
                                             const unsigned short* __restrict__ origj,
                                             const int* __restrict__ lohi,
                                             double* __restrict__ acc,
                                             unsigned* __restrict__ counter,
                                             float* __restrict__ out) {
    int col = blockIdx.x >> 6;   // 0..7
    int rg  = blockIdx.x & 63;   // 0..63 (32 rows each)
    __shared__ float4 sa4[N / 2];   // 16 KB sorted {s,A} pairs
    __shared__ unsigned sow[N / 2]; // 4 KB  origj pairs (u16x2)
    __shared__ double bsum[8];
    int tid = threadIdx.x;
    int wave = tid >> 6, lane = tid & 63;

    const float4* p4 = (const float4*)(psort + (size_t)col * N);
    const unsigned* g4 = (const unsigned*)(origj + (size_t)col * N);
    #pragma unroll
    for (int k = 0; k < 2; ++k) {
        int i = tid + (k << 9);
        sa4[i] = p4[i];
        sow[i] = g4[i];
    }
    __syncthreads();

    int row0 = (rg << 5) + (wave << 2);   // 4 rows per wave, 8 waves
    float sc0 = (float)(N - 1 - 2 * row0);

    int lh[4];
    #pragma unroll
    for (int c = 0; c < 4; ++c) lh[c] = lohi[col * N + row0 + c];

    // pass 1: max of row 0 (max is permutation-invariant, bitwise)
    float m = -INFINITY;
    #pragma unroll
    for (int k = 0; k < 16; ++k) {
        float4 q = sa4[lane + (k << 6)];
        float t0 = fmaf(sc0, q.x, -q.y);
        float t1 = fmaf(sc0, q.z, -q.w);
        m = fmaxf(m, fmaxf(t0, t1));
    }
    #pragma unroll
    for (int off = 32; off > 0; off >>= 1)
        m = fmaxf(m, __shfl_xor(m, off, 64));

    // pass 2: se_c sums + build skipmask (E==+0 adds nothing: skip is exact)
    unsigned skipmask = 0u;
    float se0 = 0.0f, se1 = 0.0f, se2 = 0.0f, se3 = 0.0f;
    #pragma unroll
    for (int k = 0; k < 16; ++k) {
        float4 q = sa4[lane + (k << 6)];
        float Ea = fexp2(fmaf(sc0, q.x, -q.y) - m);
        float Eb = fexp2(fmaf(sc0, q.z, -q.w) - m);
        if (__all((Ea == 0.0f) & (Eb == 0.0f))) {
            skipmask |= (1u << k);
            continue;
        }
        {
            float g = fexp2(-(q.x + q.x));
            float E = Ea;
            se0 += E; E *= g;
            se1 += E; E *= g;
            se2 += E; E *= g;
            se3 += E;
        }
        {
            float g = fexp2(-(q.z + q.z));
            float E = Eb;
            se0 += E; E *= g;
            se1 += E; E *= g;
            se2 += E; E *= g;
            se3 += E;
        }
    }
    #pragma unroll
    for (int off = 32; off > 0; off >>= 1) {
        se0 += __shfl_xor(se0, off, 64);
        se1 += __shfl_xor(se1, off, 64);
        se2 += __shfl_xor(se2, off, 64);
        se3 += __shfl_xor(se3, off, 64);
    }
    float se[4] = {se0, se1, se2, se3};

    float L2v[4], C2v[4], yv[4];
    unsigned lo[4], wl[4];
    double rbase = 0.0;
    #pragma unroll
    for (int c = 0; c < 4; ++c) {
        float L2 = flog2(se[c]);
        L2v[c] = L2;
        rbase -= 2048.0 * (double)L2;
        C2v[c] = CLAMP2 + L2;
        lo[c] = (unsigned)(lh[c] & 0xffff);
        wl[c] = (unsigned)((lh[c] >> 16) & 0xffff) - lo[c];
        yv[c] = 1.0f / (float)wl[c];
    }

    // pass 3: skipped k-iters -> zero TRANS, no dependency chain
    float a1[4] = {0.0f, 0.0f, 0.0f, 0.0f};
    float a2[4] = {0.0f, 0.0f, 0.0f, 0.0f};
    #pragma unroll
    for (int k = 0; k < 16; ++k) {
        float4 q = sa4[lane + (k << 6)];
        unsigned ow = sow[lane + (k << 6)];
        int ja = (int)(ow & 0xffffu), jb = (int)(ow >> 16);
        if ((skipmask >> k) & 1u) {
            // E == +0 for all c: mx2 == L2v[c] bitwise; only x-chain needed
            {
                float tsv = q.x + q.x;
                float x = fmaf(sc0, q.x, -q.y) - m;
                #pragma unroll
                for (int c = 0; c < 4; ++c) {
                    a1[c] += L2v[c];
                    float mx1 = fmaxf(x, C2v[c]);
                    float w = ((unsigned)(ja - lo[c]) < wl[c]) ? (mx1 - L2v[c]) : 0.0f;
                    a2[c] += w;
                    x -= tsv;
                }
            }
            {
                float tsv = q.z + q.z;
                float x = fmaf(sc0, q.z, -q.w) - m;
                #pragma unroll
                for (int c = 0; c < 4; ++c) {
                    a1[c] += L2v[c];
                    float mx1 = fmaxf(x, C2v[c]);
                    float w = ((unsigned)(jb - lo[c]) < wl[c]) ? (mx1 - L2v[c]) : 0.0f;
                    a2[c] += w;
                    x -= tsv;
                }
            }
        } else {
            {
                float tsv = q.x + q.x;
                float g = fexp2(-tsv);
                float x = fmaf(sc0, q.x, -q.y) - m;
                float E = fexp2(x);
                #pragma unroll
                for (int c = 0; c < 4; ++c) {
                    float mx2 = fmaxf(flog2(se[c] - E), C2v[c]);
                    a1[c] += mx2;
                    float mx1 = fmaxf(x, C2v[c]);
                    float w = ((unsigned)(ja - lo[c]) < wl[c]) ? (mx1 - mx2) : 0.0f;
                    a2[c] += w;
                    E *= g;
                    x -= tsv;
                }
            }
            {
                float tsv = q.z + q.z;
                float g = fexp2(-tsv);
                float x = fmaf(sc0, q.z, -q.w) - m;
                float E = fexp2(x);
                #pragma unroll
                for (int c = 0; c < 4; ++c) {
                    float mx2 = fmaxf(flog2(se[c] - E), C2v[c]);
                    a1[c] += mx2;
                    float mx1 = fmaxf(x, C2v[c]);
                    float w = ((unsigned)(jb - lo[c]) < wl[c]) ? (mx1 - mx2) : 0.0f;
                    a2[c] += w;
                    E *= g;
                    x -= tsv;
                }
            }
        }
    }
    float r = 0.0f;
    #pragma unroll
    for (int c = 0; c < 4; ++c) r += fmaf(yv[c], a2[c], a1[c]);
    #pragma unroll
    for (int off = 32; off > 0; off >>= 1)
        r += __shfl_xor(r, off, 64);

    if (lane == 0) bsum[wave] = rbase + (double)r;
    __syncthreads();
    if (tid == 0) {
        double tot = ((bsum[0] + bsum[1]) + (bsum[2] + bsum[3])) +
                     ((bsum[4] + bsum[5]) + (bsum[6] + bsum[7]));
        atomicAdd(&acc[col], LN2_D * tot);
        __threadfence();
        unsigned old = atomicAdd(counter, 1u);
        if (old == (unsigned)(NC * 64 - 1)) {  // last of 512 blocks
            __threadfence();
            float ssum = 0.0f;
            int cnt = 0;
            for (int c = 0; c < NC; ++c) {
                double av2 = atomicAdd(&acc[c], 0.0);  // device-scope read
                float lc = (float)(-av2 / ((double)N * (double)N));
                if (lc > 0.0f) { ssum += lc; cnt++; }
            }
            out[0] = ssum / (float)(cnt > 0 ? cnt : 1);
        }
    }
}

extern "C" void kernel_launch(void* const* d_in, const int* in_sizes, int n_in,
                              void* d_out, int out_size, void* d_ws, size_t ws_size,
                              hipStream_t stream) {
    const float* logits    = (const float*)d_in[0];
    const int*   events    = (const int*)d_in[1];
    const float* durations = (const float*)d_in[2];
    float* out = (float*)d_out;

    char* ws = (char*)d_ws;
    double*         acc     = (double*)ws;
    float2*         psort   = (float2*)(ws + 64);
    int*            lohi    = (int*)(ws + 64 + (size_t)NC * N * sizeof(float2));
    unsigned*       counter = (unsigned*)(ws + 64 + (size_t)NC * N * (sizeof(float2) + sizeof(int)));
    unsigned short* origj   = (unsigned short*)(ws + 64 + (size_t)NC * N * (sizeof(float2) + sizeof(int)) + 64);

    k_prep<<<dim3(1024), 256, 0, stream>>>(logits, durations, events, psort, origj, lohi, acc, counter);
    k_bce<<<dim3(NC * 64), 512, 0, stream>>>(psort, origj, lohi, acc, counter, out);
}